// Round 1
// baseline (335.120 us; speedup 1.0000x reference)
//
#include <hip/hip_runtime.h>

#define NROWS 262144
#define DCOLS 128
#define MARGIN_SQ 0.390625f   // (1.25/2)^2

__global__ void fra_zero_ws(float* ws) {
    if (threadIdx.x < 3) ws[threadIdx.x] = 0.0f;
}

__global__ __launch_bounds__(256) void fra_main(const float* __restrict__ o1,
                                                const float* __restrict__ o2,
                                                const float* __restrict__ desire,
                                                float* __restrict__ ws) {
    __shared__ float s_acc[3];  // inter, act, des
    if (threadIdx.x < 3) s_acc[threadIdx.x] = 0.0f;
    __syncthreads();

    const int lane          = threadIdx.x & 63;
    const int waveInBlock   = threadIdx.x >> 6;
    const int wavesPerBlock = blockDim.x >> 6;
    const int globalWave    = blockIdx.x * wavesPerBlock + waveInBlock;
    const int totalWaves    = gridDim.x * wavesPerBlock;
    const int halfLane      = lane & 31;   // float4 index within the row
    const int rowSel        = lane >> 5;   // 0 or 1: which of the wave's 2 rows

    float l_inter = 0.0f, l_act = 0.0f, l_des = 0.0f;

    const int nPairs = NROWS / 2;
    for (int pair = globalWave; pair < nPairs; pair += totalWaves) {
        const int row = pair * 2 + rowSel;
        const float4* __restrict__ a =
            (const float4*)(o1 + (size_t)row * DCOLS);
        const float4* __restrict__ b =
            (const float4*)(o2 + (size_t)row * DCOLS);
        const float4 va = a[halfLane];
        const float4 vb = b[halfLane];
        const float dx = va.x - vb.x;
        const float dy = va.y - vb.y;
        const float dz = va.z - vb.z;
        const float dw = va.w - vb.w;
        float acc = dx * dx + dy * dy + dz * dz + dw * dw;

        // reduce dist^2 across each 32-lane half-wave (masks <32 stay in-group)
        acc += __shfl_xor(acc, 16);
        acc += __shfl_xor(acc, 8);
        acc += __shfl_xor(acc, 4);
        acc += __shfl_xor(acc, 2);
        acc += __shfl_xor(acc, 1);

        if (halfLane == 0) {
            const float d   = desire[row];
            const float act = (acc > MARGIN_SQ) ? 1.0f : 0.0f;
            l_act   += act;
            l_des   += d;
            l_inter += act * d;
        }
    }

    if (halfLane == 0) {
        atomicAdd(&s_acc[0], l_inter);
        atomicAdd(&s_acc[1], l_act);
        atomicAdd(&s_acc[2], l_des);
    }
    __syncthreads();
    if (threadIdx.x == 0) {
        atomicAdd(&ws[0], s_acc[0]);
        atomicAdd(&ws[1], s_acc[1]);
        atomicAdd(&ws[2], s_acc[2]);
    }
}

__global__ void fra_final(const float* __restrict__ ws, float* __restrict__ out) {
    const float inter = ws[0];
    const float uni   = ws[1] + ws[2] - inter;
    out[0] = (inter + 1e-6f) / (uni + 1e-6f);
}

extern "C" void kernel_launch(void* const* d_in, const int* in_sizes, int n_in,
                              void* d_out, int out_size, void* d_ws, size_t ws_size,
                              hipStream_t stream) {
    const float* o1     = (const float*)d_in[0];
    const float* o2     = (const float*)d_in[1];
    const float* desire = (const float*)d_in[2];
    float*       out    = (float*)d_out;
    float*       ws     = (float*)d_ws;

    fra_zero_ws<<<1, 64, 0, stream>>>(ws);

    // 2048 blocks x 256 threads = 8192 waves; each wave streams 16 row-pairs.
    fra_main<<<2048, 256, 0, stream>>>(o1, o2, desire, ws);

    fra_final<<<1, 1, 0, stream>>>(ws, out);
}

// Round 2
// 284.049 us; speedup vs baseline: 1.1798x; 1.1798x over previous
//
#include <hip/hip_runtime.h>

#define NROWS   262144
#define DCOLS   128
#define NBLOCKS 2048
#define MARGIN_SQ 0.390625f   // (1.25/2)^2

// Layout: 8 lanes per row. lane = rg*8 + c, rg = row-in-group (0..7),
// c = 64B-chunk (0..7). One load instruction (fixed k) covers 8 rows x
// 128B contiguous chunk -> every 128B line fully consumed.
// A wave processes 4 groups of 8 rows = 32 contiguous rows.
__global__ __launch_bounds__(256) void fra_main(const float* __restrict__ o1,
                                                const float* __restrict__ o2,
                                                const float* __restrict__ desire,
                                                float* __restrict__ ws) {
    __shared__ float s_inter[4], s_act[4], s_des[4];
    const int tid  = threadIdx.x;
    const int lane = tid & 63;
    const int wave = tid >> 6;          // 0..3
    const int c    = lane & 7;          // chunk within row
    const int rg   = lane >> 3;         // row within group (0..7)
    const int globalWave = blockIdx.x * 4 + wave;   // 0..8191
    const int group0 = globalWave * 4;              // 4 groups/wave, exact cover

    float l_inter = 0.0f, l_act = 0.0f, l_des = 0.0f;

    #pragma unroll
    for (int gg = 0; gg < 4; gg += 2) {
        const int g0 = group0 + gg;
        const int g1 = g0 + 1;
        const size_t r0 = (size_t)(g0 * 8 + rg) * DCOLS;
        const size_t r1 = (size_t)(g1 * 8 + rg) * DCOLS;
        const float4* __restrict__ a0 = (const float4*)(o1 + r0) + c;
        const float4* __restrict__ b0 = (const float4*)(o2 + r0) + c;
        const float4* __restrict__ a1 = (const float4*)(o1 + r1) + c;
        const float4* __restrict__ b1 = (const float4*)(o2 + r1) + c;

        // Issue all 16 loads before any dependent math (max MLP).
        float4 va0[4], vb0[4], va1[4], vb1[4];
        #pragma unroll
        for (int k = 0; k < 4; k++) {
            va0[k] = a0[k * 8];
            va1[k] = a1[k * 8];
            vb0[k] = b0[k * 8];
            vb1[k] = b1[k * 8];
        }

        float acc0 = 0.0f, acc1 = 0.0f;
        #pragma unroll
        for (int k = 0; k < 4; k++) {
            float dx = va0[k].x - vb0[k].x;
            float dy = va0[k].y - vb0[k].y;
            float dz = va0[k].z - vb0[k].z;
            float dw = va0[k].w - vb0[k].w;
            acc0 += dx * dx + dy * dy + dz * dz + dw * dw;
            dx = va1[k].x - vb1[k].x;
            dy = va1[k].y - vb1[k].y;
            dz = va1[k].z - vb1[k].z;
            dw = va1[k].w - vb1[k].w;
            acc1 += dx * dx + dy * dy + dz * dz + dw * dw;
        }

        // Row sum: reduce across c (3 steps, two independent chains pipeline).
        acc0 += __shfl_xor(acc0, 1);
        acc1 += __shfl_xor(acc1, 1);
        acc0 += __shfl_xor(acc0, 2);
        acc1 += __shfl_xor(acc1, 2);
        acc0 += __shfl_xor(acc0, 4);
        acc1 += __shfl_xor(acc1, 4);

        if (c == 0) {
            const float d0 = desire[g0 * 8 + rg];
            const float d1 = desire[g1 * 8 + rg];
            const float act0 = (acc0 > MARGIN_SQ) ? 1.0f : 0.0f;
            const float act1 = (acc1 > MARGIN_SQ) ? 1.0f : 0.0f;
            l_act   += act0 + act1;
            l_des   += d0 + d1;
            l_inter += act0 * d0 + act1 * d1;
        }
    }

    // Sum the 8 c==0 lanes (others hold 0): xor over rg bits {8,16,32}.
    l_inter += __shfl_xor(l_inter, 8);
    l_act   += __shfl_xor(l_act,   8);
    l_des   += __shfl_xor(l_des,   8);
    l_inter += __shfl_xor(l_inter, 16);
    l_act   += __shfl_xor(l_act,   16);
    l_des   += __shfl_xor(l_des,   16);
    l_inter += __shfl_xor(l_inter, 32);
    l_act   += __shfl_xor(l_act,   32);
    l_des   += __shfl_xor(l_des,   32);

    if (lane == 0) {
        s_inter[wave] = l_inter;
        s_act[wave]   = l_act;
        s_des[wave]   = l_des;
    }
    __syncthreads();
    if (tid == 0) {
        // Distinct slots per block: no init needed, no atomic contention.
        ws[blockIdx.x]               = s_inter[0] + s_inter[1] + s_inter[2] + s_inter[3];
        ws[NBLOCKS + blockIdx.x]     = s_act[0]   + s_act[1]   + s_act[2]   + s_act[3];
        ws[2 * NBLOCKS + blockIdx.x] = s_des[0]   + s_des[1]   + s_des[2]   + s_des[3];
    }
}

__global__ __launch_bounds__(1024) void fra_reduce(const float* __restrict__ ws,
                                                   float* __restrict__ out) {
    __shared__ float s[3][16];
    const int t = threadIdx.x;
    float i = ws[t]            + ws[t + 1024];
    float a = ws[2048 + t]     + ws[2048 + t + 1024];
    float d = ws[4096 + t]     + ws[4096 + t + 1024];

    #pragma unroll
    for (int off = 32; off >= 1; off >>= 1) {
        i += __shfl_xor(i, off);
        a += __shfl_xor(a, off);
        d += __shfl_xor(d, off);
    }
    const int lane = t & 63, w = t >> 6;
    if (lane == 0) { s[0][w] = i; s[1][w] = a; s[2][w] = d; }
    __syncthreads();
    if (t == 0) {
        float ti = 0.0f, ta = 0.0f, td = 0.0f;
        #pragma unroll
        for (int k = 0; k < 16; k++) { ti += s[0][k]; ta += s[1][k]; td += s[2][k]; }
        const float uni = ta + td - ti;
        out[0] = (ti + 1e-6f) / (uni + 1e-6f);
    }
}

extern "C" void kernel_launch(void* const* d_in, const int* in_sizes, int n_in,
                              void* d_out, int out_size, void* d_ws, size_t ws_size,
                              hipStream_t stream) {
    const float* o1     = (const float*)d_in[0];
    const float* o2     = (const float*)d_in[1];
    const float* desire = (const float*)d_in[2];
    float*       out    = (float*)d_out;
    float*       ws     = (float*)d_ws;

    fra_main<<<NBLOCKS, 256, 0, stream>>>(o1, o2, desire, ws);
    fra_reduce<<<1, 1024, 0, stream>>>(ws, out);
}

// Round 4
// 251.248 us; speedup vs baseline: 1.3338x; 1.1306x over previous
//
#include <hip/hip_runtime.h>

#define NROWS   262144
#define DCOLS   128
#define NBLOCKS 2048
#define MARGIN_SQ 0.390625f   // (1.25/2)^2

// Native clang vector type: __builtin_nontemporal_load requires a scalar or
// true vector pointee (HIP_vector_type/float4 is a struct -> rejected).
typedef float v4f __attribute__((ext_vector_type(4)));

// Layout: 8 lanes per row (lane = rg*8 + c). Per gg-iteration a wave covers
// 2 groups x 8 rows; 16 nontemporal dwordx4 loads are issued in EXACT
// consumption order (a,b pairs) so the compiler can stage vmcnt waits
// instead of draining. No divergent branches inside the loop: all 8 c-lanes
// of a row redundantly accumulate act/desire; final sum is scaled by 1/8.
__global__ __launch_bounds__(256) void fra_main(const float* __restrict__ o1,
                                                const float* __restrict__ o2,
                                                const float* __restrict__ desire,
                                                float* __restrict__ ws) {
    __shared__ float s_inter[4], s_act[4], s_des[4];
    const int tid  = threadIdx.x;
    const int lane = tid & 63;
    const int wave = tid >> 6;          // 0..3
    const int c    = lane & 7;          // 16B chunk column
    const int rg   = lane >> 3;         // row within group
    const int gw   = blockIdx.x * 4 + wave;   // 0..8191

    float l_inter = 0.0f, l_act = 0.0f, l_des = 0.0f;

    #pragma unroll
    for (int gg = 0; gg < 2; gg++) {
        const int g0   = gw * 4 + gg * 2;
        const int row0 = g0 * 8 + rg;
        const int row1 = row0 + 8;
        const v4f* __restrict__ a0 = (const v4f*)(o1 + (size_t)row0 * DCOLS) + c;
        const v4f* __restrict__ b0 = (const v4f*)(o2 + (size_t)row0 * DCOLS) + c;
        const v4f* __restrict__ a1 = (const v4f*)(o1 + (size_t)row1 * DCOLS) + c;
        const v4f* __restrict__ b1 = (const v4f*)(o2 + (size_t)row1 * DCOLS) + c;

        // Issue all 16 loads, interleaved in consumption order.
        v4f va0[4], vb0[4], va1[4], vb1[4];
        #pragma unroll
        for (int k = 0; k < 4; k++) {
            va0[k] = __builtin_nontemporal_load(&a0[k * 8]);
            vb0[k] = __builtin_nontemporal_load(&b0[k * 8]);
        }
        #pragma unroll
        for (int k = 0; k < 4; k++) {
            va1[k] = __builtin_nontemporal_load(&a1[k * 8]);
            vb1[k] = __builtin_nontemporal_load(&b1[k * 8]);
        }

        float acc0 = 0.0f, acc1 = 0.0f;
        #pragma unroll
        for (int k = 0; k < 4; k++) {
            const v4f d = va0[k] - vb0[k];
            acc0 += d.x * d.x + d.y * d.y + d.z * d.z + d.w * d.w;
        }
        #pragma unroll
        for (int k = 0; k < 4; k++) {
            const v4f d = va1[k] - vb1[k];
            acc1 += d.x * d.x + d.y * d.y + d.z * d.z + d.w * d.w;
        }

        // Row sums across the 8 c-lanes (xor 1,2,4 -> DPP-friendly, fast).
        acc0 += __shfl_xor(acc0, 1);
        acc1 += __shfl_xor(acc1, 1);
        acc0 += __shfl_xor(acc0, 2);
        acc1 += __shfl_xor(acc1, 2);
        acc0 += __shfl_xor(acc0, 4);
        acc1 += __shfl_xor(acc1, 4);

        // All lanes accumulate (8x redundancy over c, divided out later).
        const float d0   = desire[row0];
        const float d1   = desire[row1];
        const float act0 = (acc0 > MARGIN_SQ) ? 1.0f : 0.0f;
        const float act1 = (acc1 > MARGIN_SQ) ? 1.0f : 0.0f;
        l_act   += act0 + act1;
        l_des   += d0 + d1;
        l_inter += act0 * d0 + act1 * d1;
    }

    // Full-wave sum (each row counted 8x -> scale by 1/8 at the end).
    #pragma unroll
    for (int off = 1; off <= 32; off <<= 1) {
        l_inter += __shfl_xor(l_inter, off);
        l_act   += __shfl_xor(l_act,   off);
        l_des   += __shfl_xor(l_des,   off);
    }

    if (lane == 0) {
        s_inter[wave] = l_inter * 0.125f;
        s_act[wave]   = l_act   * 0.125f;
        s_des[wave]   = l_des   * 0.125f;
    }
    __syncthreads();
    if (tid == 0) {
        ws[blockIdx.x]               = s_inter[0] + s_inter[1] + s_inter[2] + s_inter[3];
        ws[NBLOCKS + blockIdx.x]     = s_act[0]   + s_act[1]   + s_act[2]   + s_act[3];
        ws[2 * NBLOCKS + blockIdx.x] = s_des[0]   + s_des[1]   + s_des[2]   + s_des[3];
    }
}

__global__ __launch_bounds__(1024) void fra_reduce(const float* __restrict__ ws,
                                                   float* __restrict__ out) {
    __shared__ float s[3][16];
    const int t = threadIdx.x;
    float i = ws[t]        + ws[t + 1024];
    float a = ws[2048 + t] + ws[2048 + t + 1024];
    float d = ws[4096 + t] + ws[4096 + t + 1024];

    #pragma unroll
    for (int off = 32; off >= 1; off >>= 1) {
        i += __shfl_xor(i, off);
        a += __shfl_xor(a, off);
        d += __shfl_xor(d, off);
    }
    const int lane = t & 63, w = t >> 6;
    if (lane == 0) { s[0][w] = i; s[1][w] = a; s[2][w] = d; }
    __syncthreads();
    if (t == 0) {
        float ti = 0.0f, ta = 0.0f, td = 0.0f;
        #pragma unroll
        for (int k = 0; k < 16; k++) { ti += s[0][k]; ta += s[1][k]; td += s[2][k]; }
        const float uni = ta + td - ti;
        out[0] = (ti + 1e-6f) / (uni + 1e-6f);
    }
}

extern "C" void kernel_launch(void* const* d_in, const int* in_sizes, int n_in,
                              void* d_out, int out_size, void* d_ws, size_t ws_size,
                              hipStream_t stream) {
    const float* o1     = (const float*)d_in[0];
    const float* o2     = (const float*)d_in[1];
    const float* desire = (const float*)d_in[2];
    float*       out    = (float*)d_out;
    float*       ws     = (float*)d_ws;

    fra_main<<<NBLOCKS, 256, 0, stream>>>(o1, o2, desire, ws);
    fra_reduce<<<1, 1024, 0, stream>>>(ws, out);
}